// Round 2
// baseline (376.643 us; speedup 1.0000x reference)
//
#include <hip/hip_runtime.h>

// Problem constants
#define NB     64
#define CCH    256
#define HW     20480       // 128*160
#define NBATCH 4
#define NPIX   (NBATCH*HW) // 81920
#define NIDXBLK (NPIX/256) // 320

// Workspace layout (bytes), total 303752 (must stay <= harness ws_size; 344576 known OK)
//   sums [2][64][256] f32 @ 0        (131072)  zeroed by k_idx
//   hist [320][65]   u16  @ 131072   (41600)
//   idx  [81920]     u8   @ 172672   (81920)   dead after k_sums
//   pS   [64][256]   f32  @ 172672   (aliases idx region — written in k_tail1)
//   pT   [64][256]   f32  @ 238208
//   acc  f32              @ 303744   zeroed by k_idx
//   ticket u32            @ 303748   zeroed by k_idx
#define WS_SUMS   0
#define WS_HIST   131072
#define WS_IDX    172672
#define WS_PS     172672
#define WS_PT     238208
#define WS_ACC    303744
#define WS_TICKET 303748

// ---------------------------------------------------------------------------
// K1: bin index per pixel + per-block histogram (no global atomics),
// and zero-init sums/acc/ticket for the downstream kernels.
__global__ __launch_bounds__(256) void k_idx(const float* __restrict__ depth,
                                             unsigned char* __restrict__ idx,
                                             unsigned short* __restrict__ hist,
                                             float* __restrict__ sums,
                                             float* __restrict__ acc,
                                             unsigned int* __restrict__ ticket) {
    __shared__ int h[NB + 1];
    int t = threadIdx.x, blk = blockIdx.x;
    if (t < NB + 1) h[t] = 0;
    __syncthreads();
    int p = blk * 256 + t;
    float f = depth[p] * 64.0f;
    int b;
    if (!(f >= 0.0f) || f > 64.0f) b = NB;   // catches NaN via !(f>=0)
    else b = (int)f;                         // f==64.0 -> bin 64 (matches ref)
    idx[p] = (unsigned char)b;
    atomicAdd(&h[b], 1);
    if (p < 2 * NB * CCH) sums[p] = 0.0f;    // zero sums[2][64][256]
    if (p == 0) { *acc = 0.0f; *ticket = 0u; }
    __syncthreads();
    if (t < NB + 1) hist[blk * (NB + 1) + t] = (unsigned short)h[t];
}

// ---------------------------------------------------------------------------
// K2 (hot): per-(tensor,n,c) plane -> per-bin sums.
// LDS bins privatized 16 ways (group = lane&15) with +2 pad so bank =
// (2*group + bin) & 31 spreads uniformly (2 lanes/bank avg = free per m136).
__global__ __launch_bounds__(256) void k_sums(const float* __restrict__ predsS,
                                              const float* __restrict__ predsT,
                                              const unsigned char* __restrict__ idx,
                                              float* __restrict__ sums) {
    int blk = blockIdx.x;            // 2048 blocks
    int tensor = blk & 1;
    int cn = blk >> 1;
    int c = cn & 255;
    int n = cn >> 8;
    const float* src = (tensor ? predsT : predsS) + (size_t)(n * CCH + c) * HW;
    const float4* plane = (const float4*)src;
    const uchar4* id = (const uchar4*)(idx + (size_t)n * HW);

    __shared__ float bins[16][NB + 2];
    int t = threadIdx.x;
    for (int i = t; i < 16 * (NB + 2); i += 256) ((float*)bins)[i] = 0.0f;
    __syncthreads();
    float* mb = bins[t & 15];

    #pragma unroll 4
    for (int k = 0; k < HW / 4 / 256; ++k) {   // 20 iterations
        int i = t + k * 256;
        float4 v = plane[i];
        uchar4 q = id[i];
        if (q.x < NB) atomicAdd(&mb[q.x], v.x);
        if (q.y < NB) atomicAdd(&mb[q.y], v.y);
        if (q.z < NB) atomicAdd(&mb[q.z], v.z);
        if (q.w < NB) atomicAdd(&mb[q.w], v.w);
    }
    __syncthreads();
    if (t < NB) {
        float s = 0.0f;
        #pragma unroll
        for (int g = 0; g < 16; ++g) s += bins[g][t];
        atomicAdd(&sums[(tensor * NB + t) * CCH + c], s);
    }
}

// ---------------------------------------------------------------------------
// K3: single block, 1024 threads. Phase A: reduce per-block histograms to
// counts. Phase B: means + L2-normalize -> prototypes (global pS/pT).
__global__ __launch_bounds__(1024) void k_tail1(const unsigned short* __restrict__ hist,
                                                const float* __restrict__ sums,
                                                float* __restrict__ pS,
                                                float* __restrict__ pT) {
    int t = threadIdx.x;
    __shared__ int cnti[NB];
    __shared__ float cntf[NB];
    __shared__ float nw[16];

    // Phase A: counts[b] = sum over 320 blocks of hist[blk][b]
    if (t < NB) cnti[t] = 0;
    __syncthreads();
    {
        int b = t & 63;
        int chunk = t >> 6;          // 16 chunks x 20 blocks = 320
        int s = 0;
        #pragma unroll
        for (int k = 0; k < 20; ++k)
            s += (int)hist[(chunk * 20 + k) * (NB + 1) + b];
        atomicAdd(&cnti[b], s);
    }
    __syncthreads();
    if (t < NB) cntf[t] = (float)(cnti[t] < 1 ? 1 : cnti[t]);
    __syncthreads();

    // Phase B: protos. 1024 threads = 4 bins x 256 channels per pass.
    int bl = t >> 8;                 // bin-local 0..3
    int c = t & 255;
    int wv = t >> 6;                 // wave 0..15
    for (int tensor = 0; tensor < 2; ++tensor) {
        float* dst = tensor ? pT : pS;
        for (int grp = 0; grp < 16; ++grp) {
            int b = grp * 4 + bl;
            float m = sums[(tensor * NB + b) * CCH + c] / cntf[b];
            float sq = m * m;
            #pragma unroll
            for (int o = 32; o; o >>= 1) sq += __shfl_xor(sq, o, 64);
            if ((t & 63) == 0) nw[wv] = sq;
            __syncthreads();
            int wg = bl << 2;
            float nrm = sqrtf(nw[wg] + nw[wg + 1] + nw[wg + 2] + nw[wg + 3]);
            dst[b * CCH + c] = m / fmaxf(nrm, 1e-12f);
            __syncthreads();
        }
    }
}

// ---------------------------------------------------------------------------
// K4: Gram diff + final. Block = row i; 256 threads = 64 cols x 4 segments.
// Last block (ticket trick) scales and writes d_out — no extra dispatch.
__global__ __launch_bounds__(256) void k_tail2(const float* __restrict__ pS,
                                               const float* __restrict__ pT,
                                               float* __restrict__ acc,
                                               unsigned int* __restrict__ ticket,
                                               float* __restrict__ out) {
    int i = blockIdx.x;
    int t = threadIdx.x;
    int j = t & 63, seg = t >> 6;    // 4 segments of 64 channels
    const float4* Si = (const float4*)(pS + i * CCH);
    const float4* Ti = (const float4*)(pT + i * CCH);
    const float4* Sj = (const float4*)(pS + j * CCH);
    const float4* Tj = (const float4*)(pT + j * CCH);
    float dS = 0.0f, dT = 0.0f;
    #pragma unroll
    for (int k = 0; k < 16; ++k) {
        int o = seg * 16 + k;
        float4 a = Si[o], b = Sj[o];
        dS += a.x * b.x + a.y * b.y + a.z * b.z + a.w * b.w;
        float4 cc = Ti[o], d = Tj[o];
        dT += cc.x * d.x + cc.y * d.y + cc.z * d.z + cc.w * d.w;
    }
    __shared__ float sS[4][64], sT[4][64];
    sS[seg][j] = dS;
    sT[seg][j] = dT;
    __syncthreads();
    if (t < 64) {
        float fS = sS[0][t] + sS[1][t] + sS[2][t] + sS[3][t];
        float fT = sT[0][t] + sT[1][t] + sT[2][t] + sT[3][t];
        float e = fS - fT;
        e = e * e;
        #pragma unroll
        for (int o = 32; o; o >>= 1) e += __shfl_xor(e, o, 64);
        if (t == 0) {
            atomicAdd(acc, e);
            __threadfence();
            unsigned int r = atomicAdd(ticket, 1u);
            if (r == NB - 1) {
                float tot = atomicAdd(acc, 0.0f);   // atomic read (L2, coherent)
                out[0] = tot * (1.0f / (float)(NB * NB));
            }
        }
    }
}

extern "C" void kernel_launch(void* const* d_in, const int* in_sizes, int n_in,
                              void* d_out, int out_size, void* d_ws, size_t ws_size,
                              hipStream_t stream) {
    const float* predsS = (const float*)d_in[0];
    const float* predsT = (const float*)d_in[1];
    const float* depth  = (const float*)d_in[2];
    char* ws = (char*)d_ws;
    float* sums = (float*)(ws + WS_SUMS);
    unsigned short* hist = (unsigned short*)(ws + WS_HIST);
    unsigned char* idx = (unsigned char*)(ws + WS_IDX);
    float* pS = (float*)(ws + WS_PS);
    float* pT = (float*)(ws + WS_PT);
    float* acc = (float*)(ws + WS_ACC);
    unsigned int* ticket = (unsigned int*)(ws + WS_TICKET);

    k_idx<<<NIDXBLK, 256, 0, stream>>>(depth, idx, hist, sums, acc, ticket);
    k_sums<<<2048, 256, 0, stream>>>(predsS, predsT, idx, sums);
    k_tail1<<<1, 1024, 0, stream>>>(hist, sums, pS, pT);
    k_tail2<<<NB, 256, 0, stream>>>(pS, pT, acc, ticket, (float*)d_out);
}